// Round 8
// baseline (214.465 us; speedup 1.0000x reference)
//
#include <hip/hip_runtime.h>

// Problem constants
#define Bx    2
#define Sx    2048
#define Dx    1024
#define Hx    16
#define NCx   (Sx/64)     // 32 chunks per sequence
#define BHx   (Bx*Hx)     // 32
#define Mx    (Bx*Sx)     // 4096

typedef float    f4 __attribute__((ext_vector_type(4)));
typedef _Float16 h8 __attribute__((ext_vector_type(8)));
typedef _Float16 h4 __attribute__((ext_vector_type(4)));

// async global->LDS, 16B per lane. LDS dest = wave-uniform base + lane*16.
__device__ __forceinline__ void gl2lds16(const _Float16* g, _Float16* l) {
  __builtin_amdgcn_global_load_lds(
      (const __attribute__((address_space(1))) void*)g,
      (__attribute__((address_space(3))) void*)l, 16, 0, 0);
}

// ---------------------------------------------------------------------------
// convert_all: R8 merge of convert_in (blocks 0..6143) and convert_w
// (blocks 6144..7167). Bodies unchanged from R7 — one dispatch fewer.
// ---------------------------------------------------------------------------
__global__ __launch_bounds__(256) void convert_all(
    const float* __restrict__ q, const float* __restrict__ k,
    const float* __restrict__ v, const float* __restrict__ qm,
    const float* __restrict__ km, const float* __restrict__ vm,
    _Float16* __restrict__ qh, _Float16* __restrict__ kh,
    _Float16* __restrict__ vh,
    const float* __restrict__ W0, const float* __restrict__ W1,
    const float* __restrict__ W2, const float* __restrict__ W3,
    _Float16* __restrict__ T0, _Float16* __restrict__ T1,
    _Float16* __restrict__ T2, _Float16* __restrict__ T3)
{
  const int bx = blockIdx.x;
  if (bx < 6144) {
    // convert_in: xh = (fp16)(x * mask[row]); 8 elems/thread.
    const int z = bx >> 11;
    const float* x = (z == 0) ? q : (z == 1) ? k : v;
    const float* m = (z == 0) ? qm : (z == 1) ? km : vm;
    _Float16*    o = (z == 0) ? qh : (z == 1) ? kh : vh;
    const int i8 = (bx & 2047) * 256 + threadIdx.x;   // 0..524287
    const f4 v0 = *(const f4*)(x + (size_t)i8 * 8);
    const f4 v1 = *(const f4*)(x + (size_t)i8 * 8 + 4);
    const float mf = m[i8 >> 7];
    h8 r;
#pragma unroll
    for (int i = 0; i < 4; i++) {
      r[i]     = (_Float16)(v0[i] * mf);
      r[4 + i] = (_Float16)(v1[i] * mf);
    }
    *(h8*)(o + (size_t)i8 * 8) = r;
  } else {
    // convert_w: Wt[n][k] = (fp16) W[k][n]
    const int idx = bx - 6144;                 // 0..1023
    const int wz = idx >> 8, rem = idx & 255;
    const int wy = rem >> 4, wx = rem & 15;
    const float* W = (wz == 0) ? W0 : (wz == 1) ? W1 : (wz == 2) ? W2 : W3;
    _Float16* T = (wz == 0) ? T0 : (wz == 1) ? T1 : (wz == 2) ? T2 : T3;
    __shared__ float Ws[64 * 68];
    const int tx = threadIdx.x & 15, ty = threadIdx.x >> 4;
    const int k0 = wy * 64, n0 = wx * 64;
#pragma unroll
    for (int i = 0; i < 4; i++) {
      const int r = ty + 16 * i;
      *(f4*)&Ws[r * 68 + tx * 4] = *(const f4*)&W[(size_t)(k0 + r) * Dx + n0 + tx * 4];
    }
    __syncthreads();
#pragma unroll
    for (int i = 0; i < 4; i++) {
      const int n = ty + 16 * i;
      h4 o;
#pragma unroll
      for (int j = 0; j < 4; j++) o[j] = (_Float16)Ws[(tx * 4 + j) * 68 + n];
      *(h4*)&T[(size_t)(n0 + n) * Dx + k0 + tx * 4] = o;
    }
  }
}

// ---------------------------------------------------------------------------
// gemm_f16: m97-style global_load_lds staging, XOR swizzle, BK=64, 512
// threads, MFMA 16x16x32_f16, bijective XCD chunk-swizzle (R5 — each A
// panel's reader blocks land on ONE XCD; panel becomes L2/L3-resident).
// fp16 A only (R1/R6 fp32-A fusion closed: barrier vmcnt(0) drain defeats
// reg prefetch).
// ---------------------------------------------------------------------------
struct GArgs {
  const _Float16* A; const _Float16* Bt; const float* bias;
  void* out; int leaky, half_out;
};

template<int BN, int WR, int WC>
__global__ __launch_bounds__(512, 4) void gemm_f16(GArgs g0, GArgs g1, GArgs g2)
{
  constexpr int GX  = Dx / BN;                 // 8 or 16 (power of 2)
  constexpr int LGX = (GX == 8) ? 3 : 4;
  const int wgp = blockIdx.x + GX * (blockIdx.y + 32 * blockIdx.z);
  const int nwg = GX * 32 * gridDim.z;         // 768 or 512, both % 8 == 0
  const int wgl = (wgp & 7) * (nwg >> 3) + (wgp >> 3);
  const int bxx = wgl & (GX - 1);
  const int byy = (wgl >> LGX) & 31;
  const int bzz = wgl >> (LGX + 5);

  const GArgs g = (bzz == 0) ? g0 : (bzz == 1) ? g1 : g2;
  constexpr int FM = 128 / WR / 16;
  constexpr int FN = BN / WC / 16;
  __shared__ _Float16 As[128 * 64];
  __shared__ _Float16 Bs[BN * 64];
  const int tid = threadIdx.x;
  const int m0 = byy * 128, n0 = bxx * BN;
  const int lane = tid & 63, wave = tid >> 6;
  const int lm = lane & 15, qd = lane >> 4;
  const int wr = wave % WR, wc = wave / WR;
  const int wm0 = wr * (128 / WR), wn0 = wc * (BN / WC);
  const int srow = lane >> 3;
  const int sseg = (lane & 7) ^ srow;
  const _Float16* gA = g.A  + (size_t)(m0 + srow) * Dx + sseg * 8;
  const _Float16* gB = g.Bt + (size_t)(n0 + srow) * Dx + sseg * 8;

  f4 acc[FM][FN];
#pragma unroll
  for (int i = 0; i < FM; i++)
#pragma unroll
    for (int j = 0; j < FN; j++) { f4 z = {0.f, 0.f, 0.f, 0.f}; acc[i][j] = z; }

  for (int kt = 0; kt < Dx; kt += 64) {
    __syncthreads();
#pragma unroll
    for (int u = 0; u < 2; u++) {
      const int t = wave * 2 + u;
      gl2lds16(gA + (size_t)(t * 8) * Dx + kt, &As[t * 512]);
    }
#pragma unroll
    for (int u = 0; u < BN / 64; u++) {
      const int t = wave * (BN / 64) + u;
      gl2lds16(gB + (size_t)(t * 8) * Dx + kt, &Bs[t * 512]);
    }
    __syncthreads();
#pragma unroll
    for (int kk = 0; kk < 2; kk++) {
      const int sp = ((kk * 4 + qd) ^ (lm & 7)) * 8;
      h8 af[FM];
#pragma unroll
      for (int i = 0; i < FM; i++)
        af[i] = *(const h8*)&As[(wm0 + i * 16 + lm) * 64 + sp];
#pragma unroll
      for (int j = 0; j < FN; j++) {
        const h8 bf = *(const h8*)&Bs[(wn0 + j * 16 + lm) * 64 + sp];
#pragma unroll
        for (int i = 0; i < FM; i++)
          acc[i][j] = __builtin_amdgcn_mfma_f32_16x16x32_f16(af[i], bf, acc[i][j], 0, 0, 0);
      }
    }
  }

#pragma unroll
  for (int j = 0; j < FN; j++) {
    const int n = n0 + wn0 + j * 16 + lm;
    const float bz = g.bias[n];
#pragma unroll
    for (int i = 0; i < FM; i++) {
      const int mb = m0 + wm0 + i * 16 + qd * 4;
#pragma unroll
      for (int r = 0; r < 4; r++) {
        float v = acc[i][j][r] + bz;
        if (g.leaky) v = (v >= 0.f) ? v : 0.1f * v;
        if (g.half_out) ((_Float16*)g.out)[(size_t)(mb + r) * Dx + n] = (_Float16)v;
        else            ((float*)g.out)[(size_t)(mb + r) * Dx + n] = v;
      }
    }
  }
}

// ---------------------------------------------------------------------------
// chunkkv_mfma: S_c^T = V_c^T K_c  (64x64x64 MFMA), output fp16 [e][d]
// PER-CHUNK (R8: no longer prefixed afterwards); plus per-chunk k-sums cz.
// Transpose-scatter seg carries ^((r>>3)&7) (write-conflict fix, R4).
// ---------------------------------------------------------------------------
__global__ __launch_bounds__(256) void chunkkv_mfma(
    const _Float16* __restrict__ kp, const _Float16* __restrict__ vp,
    _Float16* __restrict__ ckvh, float* __restrict__ cz)
{
  __shared__ _Float16 Kt[64 * 64];   // [d][s] swizzled
  __shared__ _Float16 Vt[64 * 64];   // [e][s] swizzled
  const int blk = blockIdx.x;
  const int c = blk & (NCx - 1);
  const int bh = blk / NCx;
  const int b = bh / Hx, h = bh % Hx;
  const int tid = threadIdx.x;
  const size_t rowbase = ((size_t)(b * Sx + c * 64)) * Dx + h * 64;

#pragma unroll
  for (int p = 0; p < 2; p++) {
    const int f = tid + 256 * p;
    const int s = f >> 3, g8 = f & 7;
    const h8 hk = *(const h8*)&kp[rowbase + (size_t)s * Dx + g8 * 8];
    const h8 hv = *(const h8*)&vp[rowbase + (size_t)s * Dx + g8 * 8];
#pragma unroll
    for (int i = 0; i < 8; i++) {
      const int r = g8 * 8 + i;       // d for Kt, e for Vt
      const int a = r * 64 + ((((s >> 3) ^ (r & 7)) ^ ((r >> 3) & 7)) * 8) + (s & 7);
      Kt[a] = hk[i];
      Vt[a] = hv[i];
    }
  }
  __syncthreads();

  const int lane = tid & 63, w = tid >> 6;
  const int lm = lane & 15, qd = lane >> 4;

  h8 av[2];
  {
    const int rv = w * 16 + lm;
    const int xv = (rv & 7) ^ ((rv >> 3) & 7);
#pragma unroll
    for (int kk = 0; kk < 2; kk++)
      av[kk] = *(const h8*)&Vt[rv * 64 + ((((kk << 2) + qd)) ^ xv) * 8];
  }

#pragma unroll
  for (int dt = 0; dt < 4; dt++) {
    const int rk = dt * 16 + lm;
    const int xk = (rk & 7) ^ ((rk >> 3) & 7);
    f4 acc = {0.f, 0.f, 0.f, 0.f};
#pragma unroll
    for (int kk = 0; kk < 2; kk++) {
      const h8 bf = *(const h8*)&Kt[rk * 64 + ((((kk << 2) + qd)) ^ xk) * 8];
      acc = __builtin_amdgcn_mfma_f32_16x16x32_f16(av[kk], bf, acc, 0, 0, 0);
    }
#pragma unroll
    for (int r = 0; r < 4; r++) {
      const int e = w * 16 + qd * 4 + r;
      ckvh[(size_t)blk * 4096 + e * 64 + dt * 16 + lm] = (_Float16)acc[r];
    }
  }

  // cz[d] = sum_s K[s][d] (per-chunk)
  {
    const int d = tid >> 2, fr = tid & 3;
    const int dx = (d & 7) ^ ((d >> 3) & 7);
    float dp = 0.f;
#pragma unroll
    for (int j = 0; j < 2; j++) {
      const h8 kv = *(const h8*)&Kt[d * 64 + ((fr * 2 + j) ^ dx) * 8];
#pragma unroll
      for (int i = 0; i < 8; i++) dp += (float)kv[i];
    }
    dp += __shfl_xor(dp, 1);
    dp += __shfl_xor(dp, 2);
    if (fr == 0) cz[(size_t)blk * 64 + d] = dp;
  }
}

// ---------------------------------------------------------------------------
// attn_mfma: per chunk, P = tril(Q K^T) via MFMA; O = P@V + Q@S_excl via MFMA;
// den = q.z_excl + rowsum(P).
// R8: prefix fused in. Sh = fp16( fp32-sum over chunks 0..c-1 of per-chunk
// ckvh, in chunk order ) and zs = fp32-sum of per-chunk cz — exactly the
// sequence prefix_kernel produced (fp32 carry, one fp16 rounding per
// boundary) -> bit-identical operands. Qs/Ks stay gl2lds-staged with
// pre-swizzled source (R7); Vt keeps manual transpose scatter.
// ---------------------------------------------------------------------------
__global__ __launch_bounds__(256) void attn_mfma(
    const _Float16* __restrict__ qp, const _Float16* __restrict__ kp,
    const _Float16* __restrict__ vp, const _Float16* __restrict__ ckvh,
    const float* __restrict__ cz, _Float16* __restrict__ concat)
{
  __shared__ _Float16 Qs[64 * 64];   // [t][d] swizzled
  __shared__ _Float16 Ks[64 * 64];   // [s][d] swizzled; reused as Pa [t][s]
  __shared__ _Float16 Vt[64 * 64];   // [e][s] swizzled
  __shared__ _Float16 Sh[64 * 64];   // [e][d] swizzled (S_excl^T fp16)
  __shared__ float zs[64];
  __shared__ float den[64];
  const int blk = blockIdx.x;
  const int c = blk & (NCx - 1);
  const int bh = blk / NCx;
  const int b = bh / Hx, h = bh % Hx;
  const int tid = threadIdx.x;
  const int lane = tid & 63, w = tid >> 6;
  const int lm = lane & 15, qd = lane >> 4;
  const int x7 = lm & 7;
  const size_t rowbase = ((size_t)(b * Sx + c * 64)) * Dx + h * 64;

  // stage Q, K via gl2lds with pre-swizzled source (layout unchanged)
#pragma unroll
  for (int p = 0; p < 2; p++) {
    const int r  = 32 * p + 8 * w + (lane >> 3);
    const int sg = (lane & 7) ^ (r & 7);
    const int lb = (32 * p + 8 * w) * 64;     // wave-uniform LDS base
    gl2lds16(&qp[rowbase + (size_t)r * Dx + sg * 8], &Qs[lb]);
    gl2lds16(&kp[rowbase + (size_t)r * Dx + sg * 8], &Ks[lb]);
  }
  // Sh = running fp32 sum of per-chunk ckvh over chunks 0..c-1 (chunk order,
  // one fp16 rounding) — bit-identical to the old prefix_kernel output.
#pragma unroll
  for (int p = 0; p < 2; p++) {
    const int f = tid + 256 * p;
    const int r = f >> 3, sg = f & 7;
    const _Float16* src = ckvh + ((size_t)(bh * NCx)) * 4096 + r * 64 + sg * 8;
    float a[8] = {0.f, 0.f, 0.f, 0.f, 0.f, 0.f, 0.f, 0.f};
    for (int j = 0; j < c; j++) {
      const h8 vv = *(const h8*)(src + (size_t)j * 4096);
#pragma unroll
      for (int i = 0; i < 8; i++) a[i] += (float)vv[i];
    }
    h8 o;
#pragma unroll
    for (int i = 0; i < 8; i++) o[i] = (_Float16)a[i];
    *(h8*)&Sh[r * 64 + ((sg ^ (r & 7)) * 8)] = o;
  }
  // stage V transposed [e][s] (seg: ^((e>>3)&7))
#pragma unroll
  for (int p = 0; p < 2; p++) {
    const int f = tid + 256 * p;
    const int s = f >> 3, g8 = f & 7;
    const h8 hv = *(const h8*)&vp[rowbase + (size_t)s * Dx + g8 * 8];
#pragma unroll
    for (int i = 0; i < 8; i++) {
      const int e = g8 * 8 + i;
      Vt[e * 64 + ((((s >> 3) ^ (e & 7)) ^ ((e >> 3) & 7)) * 8) + (s & 7)] = hv[i];
    }
  }
  // zs = fp32 exclusive prefix of per-chunk cz (chunk order) — bit-identical.
  if (tid < 64) {
    const float* czsrc = cz + ((size_t)(bh * NCx)) * 64 + tid;
    float az = 0.f;
    for (int j = 0; j < c; j++) az += czsrc[(size_t)j * 64];
    zs[tid] = az;
  }
  __syncthreads();

  // A-frags for this wave's Q stripe (reused in phases 1 and 3)
  h8 aq[2];
#pragma unroll
  for (int kk = 0; kk < 2; kk++)
    aq[kk] = *(const h8*)&Qs[(w * 16 + lm) * 64 + (((kk << 2) + qd) ^ x7) * 8];

  // phase 1: P = Q K^T, 4 s-tiles
  f4 pc[4];
#pragma unroll
  for (int st = 0; st < 4; st++) {
    f4 z4 = {0.f, 0.f, 0.f, 0.f}; pc[st] = z4;
#pragma unroll
    for (int kk = 0; kk < 2; kk++) {
      const h8 bf = *(const h8*)&Ks[(st * 16 + lm) * 64 + (((kk << 2) + qd) ^ x7) * 8];
      pc[st] = __builtin_amdgcn_mfma_f32_16x16x32_f16(aq[kk], bf, pc[st], 0, 0, 0);
    }
  }
  // causal mask + rowsums
  float rsum[4] = {0.f, 0.f, 0.f, 0.f};
#pragma unroll
  for (int st = 0; st < 4; st++) {
    const int s = st * 16 + lm;
#pragma unroll
    for (int r = 0; r < 4; r++) {
      const int t = w * 16 + qd * 4 + r;
      float v = pc[st][r];
      v = (s <= t) ? v : 0.f;
      pc[st][r] = v;
      rsum[r] += v;
    }
  }
#pragma unroll
  for (int r = 0; r < 4; r++) {
    rsum[r] += __shfl_xor(rsum[r], 1);
    rsum[r] += __shfl_xor(rsum[r], 2);
    rsum[r] += __shfl_xor(rsum[r], 4);
    rsum[r] += __shfl_xor(rsum[r], 8);
  }
  // den[t] = q . z_excl  (t = tid>>2, quarter-dot + shfl)
  {
    const int t = tid >> 2, fr = tid & 3;
    float dp = 0.f;
#pragma unroll
    for (int j = 0; j < 2; j++) {
      const int sg = fr * 2 + j;
      const h8 qv = *(const h8*)&Qs[t * 64 + (sg ^ (t & 7)) * 8];
#pragma unroll
      for (int i = 0; i < 8; i++) dp += (float)qv[i] * zs[sg * 8 + i];
    }
    dp += __shfl_xor(dp, 1);
    dp += __shfl_xor(dp, 2);
    if (fr == 0) den[t] = dp;
  }
  __syncthreads();           // Ks reads done; den[t] written

  // write Pa (fp16, A-layout, swizzled) over Ks; fold rowsums into den
  _Float16* Pa = Ks;
#pragma unroll
  for (int st = 0; st < 4; st++) {
#pragma unroll
    for (int r = 0; r < 4; r++) {
      const int row = w * 16 + qd * 4 + r;
      Pa[row * 64 + (((st * 2 + (lm >> 3)) ^ (row & 7)) * 8) + (lm & 7)] =
          (_Float16)pc[st][r];
    }
  }
  if (lm == 0) {
#pragma unroll
    for (int r = 0; r < 4; r++) den[w * 16 + qd * 4 + r] += rsum[r];
  }
  __syncthreads();

  // phases 2+3: O = P@V + Q@S_excl  (same accumulators)
  h8 ap[2];
#pragma unroll
  for (int kk = 0; kk < 2; kk++)
    ap[kk] = *(const h8*)&Pa[(w * 16 + lm) * 64 + (((kk << 2) + qd) ^ x7) * 8];

  f4 acc[4];
#pragma unroll
  for (int et = 0; et < 4; et++) {
    const int re = et * 16 + lm;
    const int xv = (re & 7) ^ ((re >> 3) & 7);
    f4 z4 = {0.f, 0.f, 0.f, 0.f}; acc[et] = z4;
#pragma unroll
    for (int kk = 0; kk < 2; kk++) {
      const h8 bv = *(const h8*)&Vt[re * 64 + ((((kk << 2) + qd)) ^ xv) * 8];
      acc[et] = __builtin_amdgcn_mfma_f32_16x16x32_f16(ap[kk], bv, acc[et], 0, 0, 0);
    }
#pragma unroll
    for (int kk = 0; kk < 2; kk++) {
      const h8 bs = *(const h8*)&Sh[re * 64 + (((kk << 2) + qd) ^ x7) * 8];
      acc[et] = __builtin_amdgcn_mfma_f32_16x16x32_f16(aq[kk], bs, acc[et], 0, 0, 0);
    }
  }

  // epilogue: divide by den, write fp16 concat
#pragma unroll
  for (int r = 0; r < 4; r++) {
    const int row = w * 16 + qd * 4 + r;
    const float inv = 1.f / den[row];
    _Float16* orow = &concat[((size_t)(b * Sx + c * 64 + row)) * Dx + h * 64];
#pragma unroll
    for (int et = 0; et < 4; et++)
      orow[et * 16 + lm] = (_Float16)(acc[et][r] * inv);
  }
}

// ---------------------------------------------------------------------------
extern "C" void kernel_launch(void* const* d_in, const int* in_sizes, int n_in,
                              void* d_out, int out_size, void* d_ws, size_t ws_size,
                              hipStream_t stream)
{
  const float* q  = (const float*)d_in[0];
  const float* k  = (const float*)d_in[1];
  const float* v  = (const float*)d_in[2];
  const float* qm = (const float*)d_in[3];
  const float* km = (const float*)d_in[4];
  const float* vm = (const float*)d_in[5];
  const float* Wq = (const float*)d_in[6];
  const float* bq = (const float*)d_in[7];
  const float* Wk = (const float*)d_in[8];
  const float* bk = (const float*)d_in[9];
  const float* Wv = (const float*)d_in[10];
  const float* bv = (const float*)d_in[11];
  const float* Wo = (const float*)d_in[12];
  const float* bo = (const float*)d_in[13];
  float* out = (float*)d_out;

  // workspace layout (bytes), total 56.25 MB.
  char* ws = (char*)d_ws;
  _Float16* qh  = (_Float16*)(ws);                 //  8 MB
  _Float16* kh  = (_Float16*)(ws + 8388608);       //  8 MB
  _Float16* vh  = (_Float16*)(ws + 16777216);      //  8 MB
  _Float16* Wtq = (_Float16*)(ws + 25165824);      //  2 MB each
  _Float16* Wtk = (_Float16*)(ws + 27262976);
  _Float16* Wtv = (_Float16*)(ws + 29360128);
  _Float16* Wto = (_Float16*)(ws + 31457280);
  _Float16* qp  = (_Float16*)(ws + 33554432);      //  8 MB
  _Float16* kp  = (_Float16*)(ws + 41943040);      //  8 MB
  _Float16* vp  = (_Float16*)(ws + 50331648);      //  8 MB
  float*    cz  = (float*)   (ws + 58720256);      //  256 KB
  _Float16* ckvh   = qh;                           //  8 MB over dead qh
  _Float16* concat = kh;                           //  8 MB over dead kh

  convert_all<<<7168, 256, 0, stream>>>(q, k, v, qm, km, vm, qh, kh, vh,
                                        Wq, Wk, Wv, Wo, Wtq, Wtk, Wtv, Wto);

  GArgs gq = { qh, Wtq, bq, qp, 1, 1 };
  GArgs gk = { kh, Wtk, bk, kp, 1, 1 };
  GArgs gv = { vh, Wtv, bv, vp, 0, 1 };
  // BN=128 => grid (8,32,3) = 768 blocks = 3/CU, XCD-chunk-swizzled in-kernel.
  gemm_f16<128, 4, 2><<<dim3(Dx / 128, Mx / 128, 3), 512, 0, stream>>>(gq, gk, gv);

  chunkkv_mfma<<<BHx * NCx, 256, 0, stream>>>(kp, vp, ckvh, cz);
  attn_mfma<<<BHx * NCx, 256, 0, stream>>>(qp, kp, vp, ckvh, cz, concat);

  GArgs go = { concat, Wto, bo, out, 0, 0 };
  // BN=64 => grid (16,32) = 512 blocks = 2/CU, XCD-chunk-swizzled in-kernel.
  gemm_f16<64, 4, 2><<<dim3(Dx / 64, Mx / 128, 1), 512, 0, stream>>>(go, go, go);
}

// Round 9
// 194.730 us; speedup vs baseline: 1.1013x; 1.1013x over previous
//
#include <hip/hip_runtime.h>

// Problem constants
#define Bx    2
#define Sx    2048
#define Dx    1024
#define Hx    16
#define NCx   (Sx/64)     // 32 chunks per sequence
#define BHx   (Bx*Hx)     // 32
#define Mx    (Bx*Sx)     // 4096

typedef float    f4 __attribute__((ext_vector_type(4)));
typedef _Float16 h8 __attribute__((ext_vector_type(8)));
typedef _Float16 h4 __attribute__((ext_vector_type(4)));

// async global->LDS, 16B per lane. LDS dest = wave-uniform base + lane*16.
__device__ __forceinline__ void gl2lds16(const _Float16* g, _Float16* l) {
  __builtin_amdgcn_global_load_lds(
      (const __attribute__((address_space(1))) void*)g,
      (__attribute__((address_space(3))) void*)l, 16, 0, 0);
}

// ---------------------------------------------------------------------------
// convert_all: merge of convert_in (blocks 0..6143) and convert_w
// (blocks 6144..7167). Kept from R8 (harmless, one launch fewer).
// ---------------------------------------------------------------------------
__global__ __launch_bounds__(256) void convert_all(
    const float* __restrict__ q, const float* __restrict__ k,
    const float* __restrict__ v, const float* __restrict__ qm,
    const float* __restrict__ km, const float* __restrict__ vm,
    _Float16* __restrict__ qh, _Float16* __restrict__ kh,
    _Float16* __restrict__ vh,
    const float* __restrict__ W0, const float* __restrict__ W1,
    const float* __restrict__ W2, const float* __restrict__ W3,
    _Float16* __restrict__ T0, _Float16* __restrict__ T1,
    _Float16* __restrict__ T2, _Float16* __restrict__ T3)
{
  const int bx = blockIdx.x;
  if (bx < 6144) {
    // convert_in: xh = (fp16)(x * mask[row]); 8 elems/thread.
    const int z = bx >> 11;
    const float* x = (z == 0) ? q : (z == 1) ? k : v;
    const float* m = (z == 0) ? qm : (z == 1) ? km : vm;
    _Float16*    o = (z == 0) ? qh : (z == 1) ? kh : vh;
    const int i8 = (bx & 2047) * 256 + threadIdx.x;   // 0..524287
    const f4 v0 = *(const f4*)(x + (size_t)i8 * 8);
    const f4 v1 = *(const f4*)(x + (size_t)i8 * 8 + 4);
    const float mf = m[i8 >> 7];
    h8 r;
#pragma unroll
    for (int i = 0; i < 4; i++) {
      r[i]     = (_Float16)(v0[i] * mf);
      r[4 + i] = (_Float16)(v1[i] * mf);
    }
    *(h8*)(o + (size_t)i8 * 8) = r;
  } else {
    // convert_w: Wt[n][k] = (fp16) W[k][n]
    const int idx = bx - 6144;                 // 0..1023
    const int wz = idx >> 8, rem = idx & 255;
    const int wy = rem >> 4, wx = rem & 15;
    const float* W = (wz == 0) ? W0 : (wz == 1) ? W1 : (wz == 2) ? W2 : W3;
    _Float16* T = (wz == 0) ? T0 : (wz == 1) ? T1 : (wz == 2) ? T2 : T3;
    __shared__ float Ws[64 * 68];
    const int tx = threadIdx.x & 15, ty = threadIdx.x >> 4;
    const int k0 = wy * 64, n0 = wx * 64;
#pragma unroll
    for (int i = 0; i < 4; i++) {
      const int r = ty + 16 * i;
      *(f4*)&Ws[r * 68 + tx * 4] = *(const f4*)&W[(size_t)(k0 + r) * Dx + n0 + tx * 4];
    }
    __syncthreads();
#pragma unroll
    for (int i = 0; i < 4; i++) {
      const int n = ty + 16 * i;
      h4 o;
#pragma unroll
      for (int j = 0; j < 4; j++) o[j] = (_Float16)Ws[(tx * 4 + j) * 68 + n];
      *(h4*)&T[(size_t)(n0 + n) * Dx + k0 + tx * 4] = o;
    }
  }
}

// ---------------------------------------------------------------------------
// gemm_f16: m97-style global_load_lds staging, XOR swizzle, BK=64, 512
// threads, MFMA 16x16x32_f16, bijective XCD chunk-swizzle (R5 — each A
// panel's reader blocks land on ONE XCD; panel becomes L2/L3-resident).
// fp16 A only (R1/R6 fp32-A fusion closed: barrier vmcnt(0) drain defeats
// reg prefetch).
// ---------------------------------------------------------------------------
struct GArgs {
  const _Float16* A; const _Float16* Bt; const float* bias;
  void* out; int leaky, half_out;
};

template<int BN, int WR, int WC>
__global__ __launch_bounds__(512, 4) void gemm_f16(GArgs g0, GArgs g1, GArgs g2)
{
  constexpr int GX  = Dx / BN;                 // 8 or 16 (power of 2)
  constexpr int LGX = (GX == 8) ? 3 : 4;
  const int wgp = blockIdx.x + GX * (blockIdx.y + 32 * blockIdx.z);
  const int nwg = GX * 32 * gridDim.z;         // 768 or 512, both % 8 == 0
  const int wgl = (wgp & 7) * (nwg >> 3) + (wgp >> 3);
  const int bxx = wgl & (GX - 1);
  const int byy = (wgl >> LGX) & 31;
  const int bzz = wgl >> (LGX + 5);

  const GArgs g = (bzz == 0) ? g0 : (bzz == 1) ? g1 : g2;
  constexpr int FM = 128 / WR / 16;
  constexpr int FN = BN / WC / 16;
  __shared__ _Float16 As[128 * 64];
  __shared__ _Float16 Bs[BN * 64];
  const int tid = threadIdx.x;
  const int m0 = byy * 128, n0 = bxx * BN;
  const int lane = tid & 63, wave = tid >> 6;
  const int lm = lane & 15, qd = lane >> 4;
  const int wr = wave % WR, wc = wave / WR;
  const int wm0 = wr * (128 / WR), wn0 = wc * (BN / WC);
  const int srow = lane >> 3;
  const int sseg = (lane & 7) ^ srow;
  const _Float16* gA = g.A  + (size_t)(m0 + srow) * Dx + sseg * 8;
  const _Float16* gB = g.Bt + (size_t)(n0 + srow) * Dx + sseg * 8;

  f4 acc[FM][FN];
#pragma unroll
  for (int i = 0; i < FM; i++)
#pragma unroll
    for (int j = 0; j < FN; j++) { f4 z = {0.f, 0.f, 0.f, 0.f}; acc[i][j] = z; }

  for (int kt = 0; kt < Dx; kt += 64) {
    __syncthreads();
#pragma unroll
    for (int u = 0; u < 2; u++) {
      const int t = wave * 2 + u;
      gl2lds16(gA + (size_t)(t * 8) * Dx + kt, &As[t * 512]);
    }
#pragma unroll
    for (int u = 0; u < BN / 64; u++) {
      const int t = wave * (BN / 64) + u;
      gl2lds16(gB + (size_t)(t * 8) * Dx + kt, &Bs[t * 512]);
    }
    __syncthreads();
#pragma unroll
    for (int kk = 0; kk < 2; kk++) {
      const int sp = ((kk * 4 + qd) ^ (lm & 7)) * 8;
      h8 af[FM];
#pragma unroll
      for (int i = 0; i < FM; i++)
        af[i] = *(const h8*)&As[(wm0 + i * 16 + lm) * 64 + sp];
#pragma unroll
      for (int j = 0; j < FN; j++) {
        const h8 bf = *(const h8*)&Bs[(wn0 + j * 16 + lm) * 64 + sp];
#pragma unroll
        for (int i = 0; i < FM; i++)
          acc[i][j] = __builtin_amdgcn_mfma_f32_16x16x32_f16(af[i], bf, acc[i][j], 0, 0, 0);
      }
    }
  }

#pragma unroll
  for (int j = 0; j < FN; j++) {
    const int n = n0 + wn0 + j * 16 + lm;
    const float bz = g.bias[n];
#pragma unroll
    for (int i = 0; i < FM; i++) {
      const int mb = m0 + wm0 + i * 16 + qd * 4;
#pragma unroll
      for (int r = 0; r < 4; r++) {
        float v = acc[i][j][r] + bz;
        if (g.leaky) v = (v >= 0.f) ? v : 0.1f * v;
        if (g.half_out) ((_Float16*)g.out)[(size_t)(mb + r) * Dx + n] = (_Float16)v;
        else            ((float*)g.out)[(size_t)(mb + r) * Dx + n] = v;
      }
    }
  }
}

// ---------------------------------------------------------------------------
// chunkkv_mfma: S_c^T = V_c^T K_c  (64x64x64 MFMA), output fp16 [e][d];
// plus k-sums cz. Transpose-scatter seg carries ^((r>>3)&7) (write-conflict
// fix, R4); reads carry the matching XOR -> operands bit-identical.
// ---------------------------------------------------------------------------
__global__ __launch_bounds__(256) void chunkkv_mfma(
    const _Float16* __restrict__ kp, const _Float16* __restrict__ vp,
    _Float16* __restrict__ ckvh, float* __restrict__ cz)
{
  __shared__ _Float16 Kt[64 * 64];   // [d][s] swizzled
  __shared__ _Float16 Vt[64 * 64];   // [e][s] swizzled
  const int blk = blockIdx.x;
  const int c = blk & (NCx - 1);
  const int bh = blk / NCx;
  const int b = bh / Hx, h = bh % Hx;
  const int tid = threadIdx.x;
  const size_t rowbase = ((size_t)(b * Sx + c * 64)) * Dx + h * 64;

#pragma unroll
  for (int p = 0; p < 2; p++) {
    const int f = tid + 256 * p;
    const int s = f >> 3, g8 = f & 7;
    const h8 hk = *(const h8*)&kp[rowbase + (size_t)s * Dx + g8 * 8];
    const h8 hv = *(const h8*)&vp[rowbase + (size_t)s * Dx + g8 * 8];
#pragma unroll
    for (int i = 0; i < 8; i++) {
      const int r = g8 * 8 + i;       // d for Kt, e for Vt
      const int a = r * 64 + ((((s >> 3) ^ (r & 7)) ^ ((r >> 3) & 7)) * 8) + (s & 7);
      Kt[a] = hk[i];
      Vt[a] = hv[i];
    }
  }
  __syncthreads();

  const int lane = tid & 63, w = tid >> 6;
  const int lm = lane & 15, qd = lane >> 4;

  h8 av[2];
  {
    const int rv = w * 16 + lm;
    const int xv = (rv & 7) ^ ((rv >> 3) & 7);
#pragma unroll
    for (int kk = 0; kk < 2; kk++)
      av[kk] = *(const h8*)&Vt[rv * 64 + ((((kk << 2) + qd)) ^ xv) * 8];
  }

#pragma unroll
  for (int dt = 0; dt < 4; dt++) {
    const int rk = dt * 16 + lm;
    const int xk = (rk & 7) ^ ((rk >> 3) & 7);
    f4 acc = {0.f, 0.f, 0.f, 0.f};
#pragma unroll
    for (int kk = 0; kk < 2; kk++) {
      const h8 bf = *(const h8*)&Kt[rk * 64 + ((((kk << 2) + qd)) ^ xk) * 8];
      acc = __builtin_amdgcn_mfma_f32_16x16x32_f16(av[kk], bf, acc, 0, 0, 0);
    }
#pragma unroll
    for (int r = 0; r < 4; r++) {
      const int e = w * 16 + qd * 4 + r;
      ckvh[(size_t)blk * 4096 + e * 64 + dt * 16 + lm] = (_Float16)acc[r];
    }
  }

  // cz[d] = sum_s K[s][d] (per-chunk; per-row seg permutation spreads banks)
  {
    const int d = tid >> 2, fr = tid & 3;
    const int dx = (d & 7) ^ ((d >> 3) & 7);
    float dp = 0.f;
#pragma unroll
    for (int j = 0; j < 2; j++) {
      const h8 kv = *(const h8*)&Kt[d * 64 + ((fr * 2 + j) ^ dx) * 8];
#pragma unroll
      for (int i = 0; i < 8; i++) dp += (float)kv[i];
    }
    dp += __shfl_xor(dp, 1);
    dp += __shfl_xor(dp, 2);
    if (fr == 0) cz[(size_t)blk * 64 + d] = dp;
  }
}

// ---------------------------------------------------------------------------
// prefix: element-parallel exclusive scan over 32 chunks (fp16 data, fp32
// carry). Fully unrolled load-all / scan-in-regs / store-all. RESTORED as a
// separate dispatch (R8's fusion into attn serialized it per-block with
// 31x load imbalance -> +19 µs; element-parallel O(1)-depth wins).
// ---------------------------------------------------------------------------
__global__ __launch_bounds__(256) void prefix_kernel(
    _Float16* __restrict__ ckvh, float* __restrict__ cz)
{
  const int gid = blockIdx.x * 256 + threadIdx.x;   // 0..131071
  const int bh = gid >> 12, el = gid & 4095;
  const size_t base = (((size_t)bh * NCx) << 12) + el;
  float vals[NCx];
#pragma unroll
  for (int c = 0; c < NCx; c++)
    vals[c] = (float)ckvh[base + ((size_t)c << 12)];
  float acc = 0.f;
#pragma unroll
  for (int c = 0; c < NCx; c++) { const float t = vals[c]; vals[c] = acc; acc += t; }
#pragma unroll
  for (int c = 0; c < NCx; c++)
    ckvh[base + ((size_t)c << 12)] = (_Float16)vals[c];

  if (gid < BHx * 64) {
    const int zbh = gid >> 6, d = gid & 63;
    const size_t zb = (size_t)zbh * NCx * 64 + d;
    float zv[NCx];
#pragma unroll
    for (int c = 0; c < NCx; c++) zv[c] = cz[zb + (size_t)c * 64];
    float az = 0.f;
#pragma unroll
    for (int c = 0; c < NCx; c++) { const float t = zv[c]; zv[c] = az; az += t; }
#pragma unroll
    for (int c = 0; c < NCx; c++) cz[zb + (size_t)c * 64] = zv[c];
  }
}

// ---------------------------------------------------------------------------
// attn_mfma: per chunk, P = tril(Q K^T) via MFMA; O = P@V + Q@S_excl via MFMA
// (accumulated in one C-reg set); den = q.z_excl (VALU) + rowsum(P) (shfl).
// Qs/Ks/Sh staged via global_load_lds with PRE-SWIZZLED global source (R7);
// Vt keeps the manual transpose scatter (gl2lds cannot scatter).
// ---------------------------------------------------------------------------
__global__ __launch_bounds__(256) void attn_mfma(
    const _Float16* __restrict__ qp, const _Float16* __restrict__ kp,
    const _Float16* __restrict__ vp, const _Float16* __restrict__ ckvh,
    const float* __restrict__ cz, _Float16* __restrict__ concat)
{
  __shared__ _Float16 Qs[64 * 64];   // [t][d] swizzled
  __shared__ _Float16 Ks[64 * 64];   // [s][d] swizzled; reused as Pa [t][s]
  __shared__ _Float16 Vt[64 * 64];   // [e][s] swizzled
  __shared__ _Float16 Sh[64 * 64];   // [e][d] swizzled (S_excl^T fp16)
  __shared__ float zs[64];
  __shared__ float den[64];
  const int blk = blockIdx.x;
  const int c = blk & (NCx - 1);
  const int bh = blk / NCx;
  const int b = bh / Hx, h = bh % Hx;
  const int tid = threadIdx.x;
  const int lane = tid & 63, w = tid >> 6;
  const int lm = lane & 15, qd = lane >> 4;
  const int x7 = lm & 7;
  const size_t rowbase = ((size_t)(b * Sx + c * 64)) * Dx + h * 64;

  // stage Q, K, Sh via gl2lds with pre-swizzled source (layout unchanged)
#pragma unroll
  for (int p = 0; p < 2; p++) {
    const int r  = 32 * p + 8 * w + (lane >> 3);
    const int sg = (lane & 7) ^ (r & 7);
    const int lb = (32 * p + 8 * w) * 64;     // wave-uniform LDS base
    gl2lds16(&qp[rowbase + (size_t)r * Dx + sg * 8], &Qs[lb]);
    gl2lds16(&kp[rowbase + (size_t)r * Dx + sg * 8], &Ks[lb]);
    gl2lds16(&ckvh[(size_t)blk * 4096 + r * 64 + sg * 8], &Sh[lb]);
  }
  // stage V transposed [e][s] (seg: ^((e>>3)&7))
#pragma unroll
  for (int p = 0; p < 2; p++) {
    const int f = tid + 256 * p;
    const int s = f >> 3, g8 = f & 7;
    const h8 hv = *(const h8*)&vp[rowbase + (size_t)s * Dx + g8 * 8];
#pragma unroll
    for (int i = 0; i < 8; i++) {
      const int e = g8 * 8 + i;
      Vt[e * 64 + ((((s >> 3) ^ (e & 7)) ^ ((e >> 3) & 7)) * 8) + (s & 7)] = hv[i];
    }
  }
  if (tid < 64) zs[tid] = cz[(size_t)blk * 64 + tid];
  __syncthreads();

  // A-frags for this wave's Q stripe (reused in phases 1 and 3)
  h8 aq[2];
#pragma unroll
  for (int kk = 0; kk < 2; kk++)
    aq[kk] = *(const h8*)&Qs[(w * 16 + lm) * 64 + (((kk << 2) + qd) ^ x7) * 8];

  // phase 1: P = Q K^T, 4 s-tiles
  f4 pc[4];
#pragma unroll
  for (int st = 0; st < 4; st++) {
    f4 z4 = {0.f, 0.f, 0.f, 0.f}; pc[st] = z4;
#pragma unroll
    for (int kk = 0; kk < 2; kk++) {
      const h8 bf = *(const h8*)&Ks[(st * 16 + lm) * 64 + (((kk << 2) + qd) ^ x7) * 8];
      pc[st] = __builtin_amdgcn_mfma_f32_16x16x32_f16(aq[kk], bf, pc[st], 0, 0, 0);
    }
  }
  // causal mask + rowsums
  float rsum[4] = {0.f, 0.f, 0.f, 0.f};
#pragma unroll
  for (int st = 0; st < 4; st++) {
    const int s = st * 16 + lm;
#pragma unroll
    for (int r = 0; r < 4; r++) {
      const int t = w * 16 + qd * 4 + r;
      float v = pc[st][r];
      v = (s <= t) ? v : 0.f;
      pc[st][r] = v;
      rsum[r] += v;
    }
  }
#pragma unroll
  for (int r = 0; r < 4; r++) {
    rsum[r] += __shfl_xor(rsum[r], 1);
    rsum[r] += __shfl_xor(rsum[r], 2);
    rsum[r] += __shfl_xor(rsum[r], 4);
    rsum[r] += __shfl_xor(rsum[r], 8);
  }
  // den[t] = q . z_excl  (t = tid>>2, quarter-dot + shfl)
  {
    const int t = tid >> 2, fr = tid & 3;
    float dp = 0.f;
#pragma unroll
    for (int j = 0; j < 2; j++) {
      const int sg = fr * 2 + j;
      const h8 qv = *(const h8*)&Qs[t * 64 + (sg ^ (t & 7)) * 8];
#pragma unroll
      for (int i = 0; i < 8; i++) dp += (float)qv[i] * zs[sg * 8 + i];
    }
    dp += __shfl_xor(dp, 1);
    dp += __shfl_xor(dp, 2);
    if (fr == 0) den[t] = dp;
  }
  __syncthreads();           // Ks reads done; den[t] written

  // write Pa (fp16, A-layout, swizzled) over Ks; fold rowsums into den
  _Float16* Pa = Ks;
#pragma unroll
  for (int st = 0; st < 4; st++) {
#pragma unroll
    for (int r = 0; r < 4; r++) {
      const int row = w * 16 + qd * 4 + r;
      Pa[row * 64 + (((st * 2 + (lm >> 3)) ^ (row & 7)) * 8) + (lm & 7)] =
          (_Float16)pc[st][r];
    }
  }
  if (lm == 0) {
#pragma unroll
    for (int r = 0; r < 4; r++) den[w * 16 + qd * 4 + r] += rsum[r];
  }
  __syncthreads();

  // phases 2+3: O = P@V + Q@S_excl  (same accumulators)
  h8 ap[2];
#pragma unroll
  for (int kk = 0; kk < 2; kk++)
    ap[kk] = *(const h8*)&Pa[(w * 16 + lm) * 64 + (((kk << 2) + qd) ^ x7) * 8];

  f4 acc[4];
#pragma unroll
  for (int et = 0; et < 4; et++) {
    const int re = et * 16 + lm;
    const int xv = (re & 7) ^ ((re >> 3) & 7);
    f4 z4 = {0.f, 0.f, 0.f, 0.f}; acc[et] = z4;
#pragma unroll
    for (int kk = 0; kk < 2; kk++) {
      const h8 bv = *(const h8*)&Vt[re * 64 + ((((kk << 2) + qd)) ^ xv) * 8];
      acc[et] = __builtin_amdgcn_mfma_f32_16x16x32_f16(ap[kk], bv, acc[et], 0, 0, 0);
    }
#pragma unroll
    for (int kk = 0; kk < 2; kk++) {
      const h8 bs = *(const h8*)&Sh[re * 64 + (((kk << 2) + qd) ^ x7) * 8];
      acc[et] = __builtin_amdgcn_mfma_f32_16x16x32_f16(aq[kk], bs, acc[et], 0, 0, 0);
    }
  }

  // epilogue: divide by den, write fp16 concat
#pragma unroll
  for (int r = 0; r < 4; r++) {
    const int row = w * 16 + qd * 4 + r;
    const float inv = 1.f / den[row];
    _Float16* orow = &concat[((size_t)(b * Sx + c * 64 + row)) * Dx + h * 64];
#pragma unroll
    for (int et = 0; et < 4; et++)
      orow[et * 16 + lm] = (_Float16)(acc[et][r] * inv);
  }
}

// ---------------------------------------------------------------------------
extern "C" void kernel_launch(void* const* d_in, const int* in_sizes, int n_in,
                              void* d_out, int out_size, void* d_ws, size_t ws_size,
                              hipStream_t stream)
{
  const float* q  = (const float*)d_in[0];
  const float* k  = (const float*)d_in[1];
  const float* v  = (const float*)d_in[2];
  const float* qm = (const float*)d_in[3];
  const float* km = (const float*)d_in[4];
  const float* vm = (const float*)d_in[5];
  const float* Wq = (const float*)d_in[6];
  const float* bq = (const float*)d_in[7];
  const float* Wk = (const float*)d_in[8];
  const float* bk = (const float*)d_in[9];
  const float* Wv = (const float*)d_in[10];
  const float* bv = (const float*)d_in[11];
  const float* Wo = (const float*)d_in[12];
  const float* bo = (const float*)d_in[13];
  float* out = (float*)d_out;

  // workspace layout (bytes), total 56.25 MB.
  char* ws = (char*)d_ws;
  _Float16* qh  = (_Float16*)(ws);                 //  8 MB
  _Float16* kh  = (_Float16*)(ws + 8388608);       //  8 MB
  _Float16* vh  = (_Float16*)(ws + 16777216);      //  8 MB
  _Float16* Wtq = (_Float16*)(ws + 25165824);      //  2 MB each
  _Float16* Wtk = (_Float16*)(ws + 27262976);
  _Float16* Wtv = (_Float16*)(ws + 29360128);
  _Float16* Wto = (_Float16*)(ws + 31457280);
  _Float16* qp  = (_Float16*)(ws + 33554432);      //  8 MB
  _Float16* kp  = (_Float16*)(ws + 41943040);      //  8 MB
  _Float16* vp  = (_Float16*)(ws + 50331648);      //  8 MB
  float*    cz  = (float*)   (ws + 58720256);      //  256 KB
  _Float16* ckvh   = qh;                           //  8 MB over dead qh
  _Float16* concat = kh;                           //  8 MB over dead kh

  convert_all<<<7168, 256, 0, stream>>>(q, k, v, qm, km, vm, qh, kh, vh,
                                        Wq, Wk, Wv, Wo, Wtq, Wtk, Wtv, Wto);

  GArgs gq = { qh, Wtq, bq, qp, 1, 1 };
  GArgs gk = { kh, Wtk, bk, kp, 1, 1 };
  GArgs gv = { vh, Wtv, bv, vp, 0, 1 };
  // BN=128 => grid (8,32,3) = 768 blocks = 3/CU, XCD-chunk-swizzled in-kernel.
  gemm_f16<128, 4, 2><<<dim3(Dx / 128, Mx / 128, 3), 512, 0, stream>>>(gq, gk, gv);

  chunkkv_mfma<<<BHx * NCx, 256, 0, stream>>>(kp, vp, ckvh, cz);
  prefix_kernel<<<512, 256, 0, stream>>>(ckvh, cz);
  attn_mfma<<<BHx * NCx, 256, 0, stream>>>(qp, kp, vp, ckvh, cz, concat);

  GArgs go = { concat, Wto, bo, out, 0, 0 };
  // BN=64 => grid (16,32) = 512 blocks = 2/CU, XCD-chunk-swizzled in-kernel.
  gemm_f16<64, 4, 2><<<dim3(Dx / 64, Mx / 128, 1), 512, 0, stream>>>(go, go, go);
}